// Round 2
// baseline (2362.585 us; speedup 1.0000x reference)
//
#include <hip/hip_runtime.h>
#include <math.h>

// MiniTransformer fused kernel.
// One thread per token row; 4 consecutive lanes = one group (quad).
// Lane s: s==0 -> cls row (constant z_cls), s==1/2/3 -> z_m/z_c/z_t rows.
// Phase 1 (all lanes): LN1 + per-head qkv GEMV (uniform scalar-cached weights),
//   scores via quad shuffles, softmax, attn-weights out, ctx for q=0,
//   per-head partial out-projection for this lane's 16 dims of row 0.
// Phase 2 (quad-parallel row-0 epilogue): residual + LN2 (quad reduce),
//   FFN1 (32 outputs/lane), exact GELU, FFN2 (16 dims/lane), write h_i.

__global__ __launch_bounds__(256, 2)
void mini_transformer_kernel(
    const float* __restrict__ z_m,
    const float* __restrict__ z_c,
    const float* __restrict__ z_t,
    const float* __restrict__ z_cls,
    const float* __restrict__ ipw,    // (192,64)  in_proj_w[e][d]
    const float* __restrict__ ipb,    // (192)
    const float* __restrict__ out_w,  // (64,64)   out_w[e][d]
    const float* __restrict__ out_b,  // (64)
    const float* __restrict__ ln1_g,
    const float* __restrict__ ln1_b,
    const float* __restrict__ ln2_g,
    const float* __restrict__ ln2_b,
    const float* __restrict__ w1,     // (128,64)  w1[e][d]
    const float* __restrict__ b1,     // (128)
    const float* __restrict__ w2,     // (64,128)  w2[d][e]
    const float* __restrict__ b2,     // (64)
    float* __restrict__ h_out,        // (M,64)
    float* __restrict__ aw_out,       // (M,4,4)
    int M)
{
    const int tid = blockIdx.x * blockDim.x + threadIdx.x;
    const int m = tid >> 2;
    const int s = tid & 3;
    if (m >= M) return;

    // ---- load my X row ----
    const float* src;
    if (s == 0)      src = z_cls;
    else if (s == 1) src = z_m + (size_t)m * 64;
    else if (s == 2) src = z_c + (size_t)m * 64;
    else             src = z_t + (size_t)m * 64;

    float x[64];
    {
        const float4* s4 = (const float4*)src;
        #pragma unroll
        for (int t = 0; t < 16; ++t) {
            float4 vv = s4[t];
            x[4*t+0] = vv.x; x[4*t+1] = vv.y; x[4*t+2] = vv.z; x[4*t+3] = vv.w;
        }
    }

    // ---- LN1 (fully in-lane over 64 dims) ----
    float xn[64];
    {
        float mu = 0.f;
        #pragma unroll
        for (int d = 0; d < 64; ++d) mu += x[d];
        mu *= (1.f/64.f);
        float var = 0.f;
        #pragma unroll
        for (int d = 0; d < 64; ++d) { float t = x[d] - mu; var = fmaf(t, t, var); }
        var *= (1.f/64.f);
        float rstd = 1.f / sqrtf(var + 1e-5f);
        #pragma unroll
        for (int d = 0; d < 64; ++d)
            xn[d] = fmaf((x[d] - mu) * rstd, ln1_g[d], ln1_b[d]);
    }

    float ao[16];                 // out-proj accum, dims e = s*16+i of row 0
    #pragma unroll
    for (int i = 0; i < 16; ++i) ao[i] = 0.f;
    float aw[4] = {0.f, 0.f, 0.f, 0.f};   // attn weight accum (my q-row s)

    const float4* owv = (const float4*)out_w;

    #pragma unroll 1
    for (int h = 0; h < 4; ++h) {
        // qkv GEMV for my row, this head: weights are thread-uniform -> s_load
        float q[16], k[16], v[16];
        #pragma unroll
        for (int j = 0; j < 16; ++j) {
            q[j] = ipb[      h*16 + j];
            k[j] = ipb[ 64 + h*16 + j];
            v[j] = ipb[128 + h*16 + j];
        }
        #pragma unroll
        for (int j = 0; j < 16; ++j) {
            const float* wq = ipw + (      h*16 + j) * 64;
            const float* wk = ipw + ( 64 + h*16 + j) * 64;
            const float* wv = ipw + (128 + h*16 + j) * 64;
            #pragma unroll
            for (int d = 0; d < 64; ++d) {
                q[j] = fmaf(xn[d], wq[d], q[j]);
                k[j] = fmaf(xn[d], wk[d], k[j]);
                v[j] = fmaf(xn[d], wv[d], v[j]);
            }
        }

        // scores: my q-row vs all 4 k-rows of the quad, scaled by 1/sqrt(16)
        float p[4];
        #pragma unroll
        for (int kk = 0; kk < 4; ++kk) {
            float acc = 0.f;
            #pragma unroll
            for (int j = 0; j < 16; ++j)
                acc = fmaf(q[j], __shfl(k[j], kk, 4), acc);
            p[kk] = acc * 0.25f;
        }
        // softmax over the 4 scores (in-lane)
        float mx = fmaxf(fmaxf(p[0], p[1]), fmaxf(p[2], p[3]));
        float sum = 0.f;
        #pragma unroll
        for (int kk = 0; kk < 4; ++kk) { p[kk] = expf(p[kk] - mx); sum += p[kk]; }
        float rs = 1.f / sum;
        #pragma unroll
        for (int kk = 0; kk < 4; ++kk) { p[kk] *= rs; aw[kk] += p[kk]; }

        // ctx for q=0 (all lanes build full ctx_h[16])
        float ctx[16];
        #pragma unroll
        for (int j = 0; j < 16; ++j) ctx[j] = 0.f;
        #pragma unroll
        for (int kk = 0; kk < 4; ++kk) {
            float p0 = __shfl(p[kk], 0, 4);    // attn[0][kk]
            #pragma unroll
            for (int j = 0; j < 16; ++j)
                ctx[j] = fmaf(p0, __shfl(v[j], kk, 4), ctx[j]);
        }

        // partial out-projection for my 16 dims: d-range [h*16, h*16+16)
        #pragma unroll
        for (int i = 0; i < 16; ++i) {
            int e = s*16 + i;
            #pragma unroll
            for (int t = 0; t < 4; ++t) {
                float4 w4 = owv[e*16 + h*4 + t];
                ao[i] = fmaf(ctx[4*t+0], w4.x, ao[i]);
                ao[i] = fmaf(ctx[4*t+1], w4.y, ao[i]);
                ao[i] = fmaf(ctx[4*t+2], w4.z, ao[i]);
                ao[i] = fmaf(ctx[4*t+3], w4.w, ao[i]);
            }
        }
    }

    // attention weights output: mean over heads, my q-row s
    {
        float4 awv = make_float4(aw[0]*0.25f, aw[1]*0.25f, aw[2]*0.25f, aw[3]*0.25f);
        ((float4*)aw_out)[(size_t)m*4 + s] = awv;
    }

    // ---- row-0 epilogue, quad-parallel: lane s owns dims [s*16, s*16+16) ----
    float x0[16];
    #pragma unroll
    for (int i = 0; i < 16; ++i)
        x0[i] = z_cls[s*16 + i] + out_b[s*16 + i] + ao[i];

    // LN2 via quad reduction
    float pm = 0.f;
    #pragma unroll
    for (int i = 0; i < 16; ++i) pm += x0[i];
    pm += __shfl_xor(pm, 1, 4);
    pm += __shfl_xor(pm, 2, 4);
    float mu2 = pm * (1.f/64.f);
    float pv = 0.f;
    #pragma unroll
    for (int i = 0; i < 16; ++i) { float t = x0[i] - mu2; pv = fmaf(t, t, pv); }
    pv += __shfl_xor(pv, 1, 4);
    pv += __shfl_xor(pv, 2, 4);
    float rstd2 = 1.f / sqrtf(pv * (1.f/64.f) + 1e-5f);

    float yn[16];
    #pragma unroll
    for (int i = 0; i < 16; ++i)
        yn[i] = fmaf((x0[i] - mu2) * rstd2, ln2_g[s*16 + i], ln2_b[s*16 + i]);

    // gather full yn row (64) from the quad
    float ynf[64];
    #pragma unroll
    for (int t = 0; t < 4; ++t)
        #pragma unroll
        for (int i = 0; i < 16; ++i)
            ynf[t*16 + i] = __shfl(yn[i], t, 4);

    // FFN1: my 32 outputs e = s*32 + c, exact GELU
    float h1[32];
    {
        const float4* w1v = (const float4*)w1;
        #pragma unroll
        for (int c = 0; c < 32; ++c) {
            int e = s*32 + c;
            float acc = b1[e];
            #pragma unroll
            for (int t = 0; t < 16; ++t) {
                float4 w4 = w1v[e*16 + t];
                acc = fmaf(ynf[4*t+0], w4.x, acc);
                acc = fmaf(ynf[4*t+1], w4.y, acc);
                acc = fmaf(ynf[4*t+2], w4.z, acc);
                acc = fmaf(ynf[4*t+3], w4.w, acc);
            }
            h1[c] = 0.5f * acc * (1.f + erff(acc * 0.70710678118654752f));
        }
    }

    // gather full h1 (128) from the quad
    float h1f[128];
    #pragma unroll
    for (int t = 0; t < 4; ++t)
        #pragma unroll
        for (int c = 0; c < 32; ++c)
            h1f[t*32 + c] = __shfl(h1[c], t, 4);

    // FFN2 + residual for my 16 dims, then store h_i
    float outv[16];
    {
        const float4* w2v = (const float4*)w2;
        #pragma unroll
        for (int i = 0; i < 16; ++i) {
            int d = s*16 + i;
            float acc = x0[i] + b2[d];
            #pragma unroll
            for (int t = 0; t < 32; ++t) {
                float4 w4 = w2v[d*32 + t];
                acc = fmaf(h1f[4*t+0], w4.x, acc);
                acc = fmaf(h1f[4*t+1], w4.y, acc);
                acc = fmaf(h1f[4*t+2], w4.z, acc);
                acc = fmaf(h1f[4*t+3], w4.w, acc);
            }
            outv[i] = acc;
        }
    }
    float4* ho = (float4*)(h_out + (size_t)m*64 + s*16);
    #pragma unroll
    for (int t = 0; t < 4; ++t)
        ho[t] = make_float4(outv[4*t+0], outv[4*t+1], outv[4*t+2], outv[4*t+3]);
}

extern "C" void kernel_launch(void* const* d_in, const int* in_sizes, int n_in,
                              void* d_out, int out_size, void* d_ws, size_t ws_size,
                              hipStream_t stream) {
    const float* z_m   = (const float*)d_in[0];
    const float* z_c   = (const float*)d_in[1];
    const float* z_t   = (const float*)d_in[2];
    const float* z_cls = (const float*)d_in[3];
    const float* ipw   = (const float*)d_in[4];
    const float* ipb   = (const float*)d_in[5];
    const float* out_w = (const float*)d_in[6];
    const float* out_b = (const float*)d_in[7];
    const float* ln1_g = (const float*)d_in[8];
    const float* ln1_b = (const float*)d_in[9];
    const float* ln2_g = (const float*)d_in[10];
    const float* ln2_b = (const float*)d_in[11];
    const float* w1    = (const float*)d_in[12];
    const float* b1    = (const float*)d_in[13];
    const float* w2    = (const float*)d_in[14];
    const float* b2    = (const float*)d_in[15];

    const int M = in_sizes[0] / 64;      // B*N groups
    float* h_out  = (float*)d_out;                 // (M,64)
    float* aw_out = h_out + (size_t)M * 64;        // (M,4,4)

    const int threads = M * 4;
    const int block = 256;
    const int grid = (threads + block - 1) / block;

    hipLaunchKernelGGL(mini_transformer_kernel, dim3(grid), dim3(block), 0, stream,
                       z_m, z_c, z_t, z_cls, ipw, ipb, out_w, out_b,
                       ln1_g, ln1_b, ln2_g, ln2_b, w1, b1, w2, b2,
                       h_out, aw_out, M);
}

// Round 3
// 2114.896 us; speedup vs baseline: 1.1171x; 1.1171x over previous
//
#include <hip/hip_runtime.h>
#include <math.h>

// MiniTransformer fused kernel, spill-free restructure.
// One thread per token row; 4 consecutive lanes = one group (quad).
// Lane s: s==0 -> cls row (constant z_cls), s==1/2/3 -> z_m/z_c/z_t rows.
//
// Register-pressure design (the round-2 killer was scratch spills: 1.3 GB of
// HBM scratch traffic at VGPR_Count=128):
//  - x[64] overwritten in place by LN1 output (no x+xn double liveness)
//  - q,k computed first (32 regs), freed after scores; v (16) after
//  - FFN1/FFN2 use quad partial-sums + __shfl_xor butterfly (no ynf[64]/h1f[128])
//  - amdgpu_waves_per_eu(2,2) pins the backend to a 256-VGPR budget (2 waves/EU)
//    so it does not spill to reach 4 waves/EU.

__global__ __launch_bounds__(256)
__attribute__((amdgpu_waves_per_eu(2, 2)))
void mini_transformer_kernel(
    const float* __restrict__ z_m,
    const float* __restrict__ z_c,
    const float* __restrict__ z_t,
    const float* __restrict__ z_cls,
    const float* __restrict__ ipw,    // (192,64)  in_proj_w[e][d]
    const float* __restrict__ ipb,    // (192)
    const float* __restrict__ out_w,  // (64,64)   out_w[e][d]
    const float* __restrict__ out_b,  // (64)
    const float* __restrict__ ln1_g,
    const float* __restrict__ ln1_b,
    const float* __restrict__ ln2_g,
    const float* __restrict__ ln2_b,
    const float* __restrict__ w1,     // (128,64)  w1[e][d]
    const float* __restrict__ b1,     // (128)
    const float* __restrict__ w2,     // (64,128)  w2[d][e]
    const float* __restrict__ b2,     // (64)
    float* __restrict__ h_out,        // (M,64)
    float* __restrict__ aw_out,       // (M,4,4)
    int M)
{
    const int tid = blockIdx.x * blockDim.x + threadIdx.x;
    const int m = tid >> 2;
    const int s = tid & 3;
    if (m >= M) return;

    // ---- load my X row ----
    const float* src = (s == 0) ? z_cls
                     : (s == 1) ? z_m + (size_t)m * 64
                     : (s == 2) ? z_c + (size_t)m * 64
                     :            z_t + (size_t)m * 64;

    float x[64];
    {
        const float4* s4 = (const float4*)src;
        #pragma unroll
        for (int t = 0; t < 16; ++t) {
            float4 vv = s4[t];
            x[4*t+0] = vv.x; x[4*t+1] = vv.y; x[4*t+2] = vv.z; x[4*t+3] = vv.w;
        }
    }

    // ---- LN1, in place (x becomes xn) ----
    {
        float sum = 0.f;
        #pragma unroll
        for (int d = 0; d < 64; ++d) sum += x[d];
        float mu = sum * (1.f/64.f);
        float sq = 0.f;
        #pragma unroll
        for (int d = 0; d < 64; ++d) { float t = x[d] - mu; sq = fmaf(t, t, sq); }
        float rstd = 1.f / sqrtf(sq * (1.f/64.f) + 1e-5f);
        #pragma unroll
        for (int d = 0; d < 64; ++d)
            x[d] = fmaf((x[d] - mu) * rstd, ln1_g[d], ln1_b[d]);
    }

    float ao[16];                       // out-proj accum for dims e = s*16+i of row 0
    #pragma unroll
    for (int i = 0; i < 16; ++i) ao[i] = 0.f;
    float aw0 = 0.f, aw1 = 0.f, aw2 = 0.f, aw3 = 0.f;

    #pragma unroll 1
    for (int h = 0; h < 4; ++h) {
        const float* bb = ipb + h*16;

        // ---- Q,K GEMV (weights thread-uniform -> scalar cache) ----
        float q[16], k[16];
        #pragma unroll
        for (int j = 0; j < 16; ++j) { q[j] = bb[j]; k[j] = bb[64 + j]; }
        {
            const float* wq0 = ipw + (size_t)(h*16) * 64;
            #pragma unroll
            for (int j = 0; j < 16; ++j) {
                const float* wqr = wq0 + j*64;
                const float* wkr = wqr + 64*64;
                #pragma unroll
                for (int d = 0; d < 64; ++d) {
                    q[j] = fmaf(x[d], wqr[d], q[j]);
                    k[j] = fmaf(x[d], wkr[d], k[j]);
                }
            }
        }

        // ---- scores (my q-row vs quad's k-rows), softmax ----
        float p0, p1, p2, p3;
        {
            float a0 = 0.f, a1 = 0.f, a2 = 0.f, a3 = 0.f;
            #pragma unroll
            for (int j = 0; j < 16; ++j) {
                a0 = fmaf(q[j], __shfl(k[j], 0, 4), a0);
                a1 = fmaf(q[j], __shfl(k[j], 1, 4), a1);
                a2 = fmaf(q[j], __shfl(k[j], 2, 4), a2);
                a3 = fmaf(q[j], __shfl(k[j], 3, 4), a3);
            }
            p0 = a0 * 0.25f; p1 = a1 * 0.25f; p2 = a2 * 0.25f; p3 = a3 * 0.25f;
        }
        float mx = fmaxf(fmaxf(p0, p1), fmaxf(p2, p3));
        p0 = expf(p0 - mx); p1 = expf(p1 - mx); p2 = expf(p2 - mx); p3 = expf(p3 - mx);
        float rs = 1.f / (p0 + p1 + p2 + p3);
        p0 *= rs; p1 *= rs; p2 *= rs; p3 *= rs;
        aw0 += p0; aw1 += p1; aw2 += p2; aw3 += p3;

        // row-0 attention probabilities (needed by every lane for ctx)
        float c0 = __shfl(p0, 0, 4);
        float c1 = __shfl(p1, 0, 4);
        float c2 = __shfl(p2, 0, 4);
        float c3 = __shfl(p3, 0, 4);

        // ---- V GEMV ----
        float v[16];
        #pragma unroll
        for (int j = 0; j < 16; ++j) v[j] = bb[128 + j];
        {
            const float* wv0 = ipw + (size_t)(128 + h*16) * 64;
            #pragma unroll
            for (int j = 0; j < 16; ++j) {
                const float* wvr = wv0 + j*64;
                #pragma unroll
                for (int d = 0; d < 64; ++d)
                    v[j] = fmaf(x[d], wvr[d], v[j]);
            }
        }

        // ---- ctx for q=0 (all lanes hold full head-ctx) ----
        float ctx[16];
        #pragma unroll
        for (int j = 0; j < 16; ++j) {
            float t = c3 * __shfl(v[j], 3, 4);
            t = fmaf(c2, __shfl(v[j], 2, 4), t);
            t = fmaf(c1, __shfl(v[j], 1, 4), t);
            ctx[j] = fmaf(c0, __shfl(v[j], 0, 4), t);
        }

        // ---- out-projection partial for my 16 dims of row 0 ----
        #pragma unroll
        for (int i = 0; i < 16; ++i) {
            const float4* wp = (const float4*)(out_w + (size_t)(s*16 + i) * 64 + h*16);
            float a = ao[i];
            #pragma unroll
            for (int t = 0; t < 4; ++t) {
                float4 w4 = wp[t];
                a = fmaf(ctx[4*t+0], w4.x, a);
                a = fmaf(ctx[4*t+1], w4.y, a);
                a = fmaf(ctx[4*t+2], w4.z, a);
                a = fmaf(ctx[4*t+3], w4.w, a);
            }
            ao[i] = a;
        }
    }

    // ---- attention weights output (mean over heads), my q-row = s ----
    ((float4*)aw_out)[(size_t)m*4 + s] =
        make_float4(aw0*0.25f, aw1*0.25f, aw2*0.25f, aw3*0.25f);

    // ---- row-0 epilogue, quad-parallel: lane s owns dims [s*16, s*16+16) ----
    float x0[16];
    #pragma unroll
    for (int i = 0; i < 16; ++i)
        x0[i] = z_cls[s*16 + i] + out_b[s*16 + i] + ao[i];

    // LN2 via quad reduction
    float pm = 0.f;
    #pragma unroll
    for (int i = 0; i < 16; ++i) pm += x0[i];
    pm += __shfl_xor(pm, 1, 4);
    pm += __shfl_xor(pm, 2, 4);
    float mu2 = pm * (1.f/64.f);
    float pv = 0.f;
    #pragma unroll
    for (int i = 0; i < 16; ++i) { float t = x0[i] - mu2; pv = fmaf(t, t, pv); }
    pv += __shfl_xor(pv, 1, 4);
    pv += __shfl_xor(pv, 2, 4);
    float rstd2 = 1.f / sqrtf(pv * (1.f/64.f) + 1e-5f);

    float yn[16];
    #pragma unroll
    for (int i = 0; i < 16; ++i)
        yn[i] = fmaf((x0[i] - mu2) * rstd2, ln2_g[s*16 + i], ln2_b[s*16 + i]);

    // ---- FFN1: partial over my 16 yn dims for every e, butterfly-reduce;
    //      keep block eb==s (my 32 h1 outputs). No 64-reg gather. ----
    float h1[32];
    #pragma unroll
    for (int eb = 0; eb < 4; ++eb) {
        #pragma unroll
        for (int c = 0; c < 32; ++c) {
            int e = eb*32 + c;
            const float4* wp = (const float4*)(w1 + (size_t)e * 64 + s*16);
            float a = 0.f;
            #pragma unroll
            for (int t = 0; t < 4; ++t) {
                float4 w4 = wp[t];
                a = fmaf(yn[4*t+0], w4.x, a);
                a = fmaf(yn[4*t+1], w4.y, a);
                a = fmaf(yn[4*t+2], w4.z, a);
                a = fmaf(yn[4*t+3], w4.w, a);
            }
            a += __shfl_xor(a, 1, 4);
            a += __shfl_xor(a, 2, 4);
            if (eb == s) h1[c] = a + b1[e];
        }
    }
    // exact GELU on my 32 values (all lanes active)
    #pragma unroll
    for (int c = 0; c < 32; ++c) {
        float a = h1[c];
        h1[c] = 0.5f * a * (1.f + erff(a * 0.70710678118654752f));
    }

    // ---- FFN2: partial over my 32 h1 dims for every d, butterfly-reduce;
    //      keep block t==s, add residual + bias. ----
    float outv[16];
    #pragma unroll
    for (int t = 0; t < 4; ++t) {
        #pragma unroll
        for (int i = 0; i < 16; ++i) {
            int d = t*16 + i;
            const float4* wp = (const float4*)(w2 + (size_t)d * 128 + s*32);
            float a = 0.f;
            #pragma unroll
            for (int u = 0; u < 8; ++u) {
                float4 w4 = wp[u];
                a = fmaf(h1[4*u+0], w4.x, a);
                a = fmaf(h1[4*u+1], w4.y, a);
                a = fmaf(h1[4*u+2], w4.z, a);
                a = fmaf(h1[4*u+3], w4.w, a);
            }
            a += __shfl_xor(a, 1, 4);
            a += __shfl_xor(a, 2, 4);
            if (t == s) outv[i] = x0[i] + b2[d] + a;
        }
    }

    float4* ho = (float4*)(h_out + (size_t)m*64 + s*16);
    #pragma unroll
    for (int t = 0; t < 4; ++t)
        ho[t] = make_float4(outv[4*t+0], outv[4*t+1], outv[4*t+2], outv[4*t+3]);
}

extern "C" void kernel_launch(void* const* d_in, const int* in_sizes, int n_in,
                              void* d_out, int out_size, void* d_ws, size_t ws_size,
                              hipStream_t stream) {
    const float* z_m   = (const float*)d_in[0];
    const float* z_c   = (const float*)d_in[1];
    const float* z_t   = (const float*)d_in[2];
    const float* z_cls = (const float*)d_in[3];
    const float* ipw   = (const float*)d_in[4];
    const float* ipb   = (const float*)d_in[5];
    const float* out_w = (const float*)d_in[6];
    const float* out_b = (const float*)d_in[7];
    const float* ln1_g = (const float*)d_in[8];
    const float* ln1_b = (const float*)d_in[9];
    const float* ln2_g = (const float*)d_in[10];
    const float* ln2_b = (const float*)d_in[11];
    const float* w1    = (const float*)d_in[12];
    const float* b1    = (const float*)d_in[13];
    const float* w2    = (const float*)d_in[14];
    const float* b2    = (const float*)d_in[15];

    const int M = in_sizes[0] / 64;      // B*N groups
    float* h_out  = (float*)d_out;                 // (M,64)
    float* aw_out = h_out + (size_t)M * 64;        // (M,4,4)

    const int threads = M * 4;
    const int block = 256;
    const int grid = (threads + block - 1) / block;

    hipLaunchKernelGGL(mini_transformer_kernel, dim3(grid), dim3(block), 0, stream,
                       z_m, z_c, z_t, z_cls, ipw, ipb, out_w, out_b,
                       ln1_g, ln1_b, ln2_g, ln2_b, w1, b1, w2, b2,
                       h_out, aw_out, M);
}

// Round 4
// 1647.020 us; speedup vs baseline: 1.4345x; 1.2841x over previous
//
#include <hip/hip_runtime.h>
#include <math.h>

// MiniTransformer fused kernel, round 4.
// One thread per token row; 4 consecutive lanes = one group (quad).
// Lane s: s==0 -> cls row (constant z_cls), s==1/2/3 -> z_m/z_c/z_t rows.
//
// Round-3 post-mortem: spills fixed (traffic at compulsory levels) but
// amdgpu_waves_per_eu(2,2) pinned occupancy to 2 waves/SIMD -> VALUBusy 17%,
// latency-bound on scalar weight loads. This round: waves_per_eu(4) (budget
// 128 VGPR, live state ~88 -> no spill, 5 waves/SIMD) + fast erf/exp.

__device__ __forceinline__ float fast_gelu(float a) {
    // exact-erf GELU via Abramowitz-Stegun 7.1.26 (|err| < 1.5e-7)
    float y = a * 0.70710678118654752f;
    float z = fabsf(y);
    float t = __frcp_rn(fmaf(0.3275911f, z, 1.f));
    float poly = t * fmaf(t, fmaf(t, fmaf(t, fmaf(t, 1.061405429f, -1.453152027f),
                                          1.421413741f), -0.284496736f), 0.254829592f);
    float e = __expf(-y * y);
    float erfz = 1.f - poly * e;
    float erfy = (y < 0.f) ? -erfz : erfz;
    return 0.5f * a * (1.f + erfy);
}

__global__ __launch_bounds__(256)
__attribute__((amdgpu_waves_per_eu(4)))
void mini_transformer_kernel(
    const float* __restrict__ z_m,
    const float* __restrict__ z_c,
    const float* __restrict__ z_t,
    const float* __restrict__ z_cls,
    const float* __restrict__ ipw,    // (192,64)  in_proj_w[e][d]
    const float* __restrict__ ipb,    // (192)
    const float* __restrict__ out_w,  // (64,64)   out_w[e][d]
    const float* __restrict__ out_b,  // (64)
    const float* __restrict__ ln1_g,
    const float* __restrict__ ln1_b,
    const float* __restrict__ ln2_g,
    const float* __restrict__ ln2_b,
    const float* __restrict__ w1,     // (128,64)  w1[e][d]
    const float* __restrict__ b1,     // (128)
    const float* __restrict__ w2,     // (64,128)  w2[d][e]
    const float* __restrict__ b2,     // (64)
    float* __restrict__ h_out,        // (M,64)
    float* __restrict__ aw_out,       // (M,4,4)
    int M)
{
    const int tid = blockIdx.x * blockDim.x + threadIdx.x;
    const int m = tid >> 2;
    const int s = tid & 3;
    if (m >= M) return;

    // ---- load my X row ----
    const float* src = (s == 0) ? z_cls
                     : (s == 1) ? z_m + (size_t)m * 64
                     : (s == 2) ? z_c + (size_t)m * 64
                     :            z_t + (size_t)m * 64;

    float x[64];
    {
        const float4* s4 = (const float4*)src;
        #pragma unroll
        for (int t = 0; t < 16; ++t) {
            float4 vv = s4[t];
            x[4*t+0] = vv.x; x[4*t+1] = vv.y; x[4*t+2] = vv.z; x[4*t+3] = vv.w;
        }
    }

    // ---- LN1, in place (x becomes xn) ----
    {
        float sum = 0.f;
        #pragma unroll
        for (int d = 0; d < 64; ++d) sum += x[d];
        float mu = sum * (1.f/64.f);
        float sq = 0.f;
        #pragma unroll
        for (int d = 0; d < 64; ++d) { float t = x[d] - mu; sq = fmaf(t, t, sq); }
        float rstd = 1.f / sqrtf(sq * (1.f/64.f) + 1e-5f);
        #pragma unroll
        for (int d = 0; d < 64; ++d)
            x[d] = fmaf((x[d] - mu) * rstd, ln1_g[d], ln1_b[d]);
    }

    float ao[16];                       // out-proj accum for dims e = s*16+i of row 0
    #pragma unroll
    for (int i = 0; i < 16; ++i) ao[i] = 0.f;
    float aw0 = 0.f, aw1 = 0.f, aw2 = 0.f, aw3 = 0.f;

    #pragma unroll 1
    for (int h = 0; h < 4; ++h) {
        const float* bb = ipb + h*16;

        // ---- Q,K GEMV (weights thread-uniform -> scalar cache) ----
        float q[16], k[16];
        #pragma unroll
        for (int j = 0; j < 16; ++j) { q[j] = bb[j]; k[j] = bb[64 + j]; }
        {
            const float* wq0 = ipw + (size_t)(h*16) * 64;
            #pragma unroll
            for (int j = 0; j < 16; ++j) {
                const float* wqr = wq0 + j*64;
                const float* wkr = wqr + 64*64;
                #pragma unroll
                for (int d = 0; d < 64; ++d) {
                    q[j] = fmaf(x[d], wqr[d], q[j]);
                    k[j] = fmaf(x[d], wkr[d], k[j]);
                }
            }
        }

        // ---- scores (my q-row vs quad's k-rows), softmax ----
        float p0, p1, p2, p3;
        {
            float a0 = 0.f, a1 = 0.f, a2 = 0.f, a3 = 0.f;
            #pragma unroll
            for (int j = 0; j < 16; ++j) {
                a0 = fmaf(q[j], __shfl(k[j], 0, 4), a0);
                a1 = fmaf(q[j], __shfl(k[j], 1, 4), a1);
                a2 = fmaf(q[j], __shfl(k[j], 2, 4), a2);
                a3 = fmaf(q[j], __shfl(k[j], 3, 4), a3);
            }
            p0 = a0 * 0.25f; p1 = a1 * 0.25f; p2 = a2 * 0.25f; p3 = a3 * 0.25f;
        }
        float mx = fmaxf(fmaxf(p0, p1), fmaxf(p2, p3));
        p0 = __expf(p0 - mx); p1 = __expf(p1 - mx);
        p2 = __expf(p2 - mx); p3 = __expf(p3 - mx);
        float rs = 1.f / (p0 + p1 + p2 + p3);
        p0 *= rs; p1 *= rs; p2 *= rs; p3 *= rs;
        aw0 += p0; aw1 += p1; aw2 += p2; aw3 += p3;

        // row-0 attention probabilities (needed by every lane for ctx)
        float c0 = __shfl(p0, 0, 4);
        float c1 = __shfl(p1, 0, 4);
        float c2 = __shfl(p2, 0, 4);
        float c3 = __shfl(p3, 0, 4);

        // ---- V GEMV ----
        float v[16];
        #pragma unroll
        for (int j = 0; j < 16; ++j) v[j] = bb[128 + j];
        {
            const float* wv0 = ipw + (size_t)(128 + h*16) * 64;
            #pragma unroll
            for (int j = 0; j < 16; ++j) {
                const float* wvr = wv0 + j*64;
                #pragma unroll
                for (int d = 0; d < 64; ++d)
                    v[j] = fmaf(x[d], wvr[d], v[j]);
            }
        }

        // ---- ctx for q=0 (all lanes hold full head-ctx) ----
        float ctx[16];
        #pragma unroll
        for (int j = 0; j < 16; ++j) {
            float t = c3 * __shfl(v[j], 3, 4);
            t = fmaf(c2, __shfl(v[j], 2, 4), t);
            t = fmaf(c1, __shfl(v[j], 1, 4), t);
            ctx[j] = fmaf(c0, __shfl(v[j], 0, 4), t);
        }

        // ---- out-projection partial for my 16 dims of row 0 ----
        #pragma unroll
        for (int i = 0; i < 16; ++i) {
            const float4* wp = (const float4*)(out_w + (size_t)(s*16 + i) * 64 + h*16);
            float a = ao[i];
            #pragma unroll
            for (int t = 0; t < 4; ++t) {
                float4 w4 = wp[t];
                a = fmaf(ctx[4*t+0], w4.x, a);
                a = fmaf(ctx[4*t+1], w4.y, a);
                a = fmaf(ctx[4*t+2], w4.z, a);
                a = fmaf(ctx[4*t+3], w4.w, a);
            }
            ao[i] = a;
        }
    }

    // ---- attention weights output (mean over heads), my q-row = s ----
    ((float4*)aw_out)[(size_t)m*4 + s] =
        make_float4(aw0*0.25f, aw1*0.25f, aw2*0.25f, aw3*0.25f);

    // ---- row-0 epilogue, quad-parallel: lane s owns dims [s*16, s*16+16) ----
    float x0[16];
    #pragma unroll
    for (int i = 0; i < 16; ++i)
        x0[i] = z_cls[s*16 + i] + out_b[s*16 + i] + ao[i];

    // LN2 via quad reduction
    float pm = 0.f;
    #pragma unroll
    for (int i = 0; i < 16; ++i) pm += x0[i];
    pm += __shfl_xor(pm, 1, 4);
    pm += __shfl_xor(pm, 2, 4);
    float mu2 = pm * (1.f/64.f);
    float pv = 0.f;
    #pragma unroll
    for (int i = 0; i < 16; ++i) { float t = x0[i] - mu2; pv = fmaf(t, t, pv); }
    pv += __shfl_xor(pv, 1, 4);
    pv += __shfl_xor(pv, 2, 4);
    float rstd2 = 1.f / sqrtf(pv * (1.f/64.f) + 1e-5f);

    float yn[16];
    #pragma unroll
    for (int i = 0; i < 16; ++i)
        yn[i] = fmaf((x0[i] - mu2) * rstd2, ln2_g[s*16 + i], ln2_b[s*16 + i]);

    // ---- FFN1: partial over my 16 yn dims for every e, butterfly-reduce;
    //      keep block eb==s (my 32 h1 outputs). ----
    float h1[32];
    #pragma unroll
    for (int eb = 0; eb < 4; ++eb) {
        #pragma unroll
        for (int c = 0; c < 32; ++c) {
            int e = eb*32 + c;
            const float4* wp = (const float4*)(w1 + (size_t)e * 64 + s*16);
            float a = 0.f;
            #pragma unroll
            for (int t = 0; t < 4; ++t) {
                float4 w4 = wp[t];
                a = fmaf(yn[4*t+0], w4.x, a);
                a = fmaf(yn[4*t+1], w4.y, a);
                a = fmaf(yn[4*t+2], w4.z, a);
                a = fmaf(yn[4*t+3], w4.w, a);
            }
            a += __shfl_xor(a, 1, 4);
            a += __shfl_xor(a, 2, 4);
            if (eb == s) h1[c] = a + b1[e];
        }
    }
    // exact-form GELU (A&S erf approx) on my 32 values
    #pragma unroll
    for (int c = 0; c < 32; ++c) h1[c] = fast_gelu(h1[c]);

    // ---- FFN2: partial over my 32 h1 dims for every d, butterfly-reduce;
    //      keep block t==s, add residual + bias. ----
    float outv[16];
    #pragma unroll
    for (int t = 0; t < 4; ++t) {
        #pragma unroll
        for (int i = 0; i < 16; ++i) {
            int d = t*16 + i;
            const float4* wp = (const float4*)(w2 + (size_t)d * 128 + s*32);
            float a = 0.f;
            #pragma unroll
            for (int u = 0; u < 8; ++u) {
                float4 w4 = wp[u];
                a = fmaf(h1[4*u+0], w4.x, a);
                a = fmaf(h1[4*u+1], w4.y, a);
                a = fmaf(h1[4*u+2], w4.z, a);
                a = fmaf(h1[4*u+3], w4.w, a);
            }
            a += __shfl_xor(a, 1, 4);
            a += __shfl_xor(a, 2, 4);
            if (t == s) outv[i] = x0[i] + b2[d] + a;
        }
    }

    float4* ho = (float4*)(h_out + (size_t)m*64 + s*16);
    #pragma unroll
    for (int t = 0; t < 4; ++t)
        ho[t] = make_float4(outv[4*t+0], outv[4*t+1], outv[4*t+2], outv[4*t+3]);
}

extern "C" void kernel_launch(void* const* d_in, const int* in_sizes, int n_in,
                              void* d_out, int out_size, void* d_ws, size_t ws_size,
                              hipStream_t stream) {
    const float* z_m   = (const float*)d_in[0];
    const float* z_c   = (const float*)d_in[1];
    const float* z_t   = (const float*)d_in[2];
    const float* z_cls = (const float*)d_in[3];
    const float* ipw   = (const float*)d_in[4];
    const float* ipb   = (const float*)d_in[5];
    const float* out_w = (const float*)d_in[6];
    const float* out_b = (const float*)d_in[7];
    const float* ln1_g = (const float*)d_in[8];
    const float* ln1_b = (const float*)d_in[9];
    const float* ln2_g = (const float*)d_in[10];
    const float* ln2_b = (const float*)d_in[11];
    const float* w1    = (const float*)d_in[12];
    const float* b1    = (const float*)d_in[13];
    const float* w2    = (const float*)d_in[14];
    const float* b2    = (const float*)d_in[15];

    const int M = in_sizes[0] / 64;      // B*N groups
    float* h_out  = (float*)d_out;                 // (M,64)
    float* aw_out = h_out + (size_t)M * 64;        // (M,4,4)

    const int threads = M * 4;
    const int block = 256;
    const int grid = (threads + block - 1) / block;

    hipLaunchKernelGGL(mini_transformer_kernel, dim3(grid), dim3(block), 0, stream,
                       z_m, z_c, z_t, z_cls, ipw, ipb, out_w, out_b,
                       ln1_g, ln1_b, ln2_g, ln2_b, w1, b1, w2, b2,
                       h_out, aw_out, M);
}

// Round 7
// 397.906 us; speedup vs baseline: 5.9375x; 4.1392x over previous
//
#include <hip/hip_runtime.h>
#include <math.h>

// MiniTransformer, round 5: full bf16-MFMA rewrite (16x16x32).
// Block = 256 thr (4 waves), grid-stride over tiles of 16 groups (64 tokens).
// Weights staged once per block into LDS as bf16, row-major, XOR-swizzled
// (byte ^= (row&7)<<4) to break stride-128/256B bank conflicts (G4/T2).
// Per tile: LN1(f32) -> xn bf16 LDS -> per-wave qkv MFMA (16 tokens, C-layout
// puts group = 16-lane section, s = reg) -> scores via shfl_xor butterfly +
// in-lane softmax -> row-0 ctx in-lane -> block-wide epilogue MFMAs
// (weights-as-A: D[chan][group-row]) with LN2 via shfl_xor(16,32).
// Assumed MFMA layouts (per guide §3): A: row=l&15, k=8*(l>>4)+j;
// B: col=l&15, same k; C/D: col=l&15, row=4*(l>>4)+reg  [m89-verified].

typedef __attribute__((ext_vector_type(8))) short   short8;
typedef __attribute__((ext_vector_type(4))) float   f32x4;
typedef __attribute__((ext_vector_type(4))) unsigned short us4;
typedef __attribute__((ext_vector_type(8))) unsigned short us8;

#define MFMA16(a,b,c) __builtin_amdgcn_mfma_f32_16x16x32_bf16((a),(b),(c),0,0,0)
#define SWZ(b_, r_) (((unsigned)(b_)) ^ ((((unsigned)(r_)) & 7u) << 4))

__device__ __forceinline__ unsigned short f2bf(float f){
  union { float f; unsigned u; } v; v.f = f;
  unsigned r = v.u + 0x7FFFu + ((v.u >> 16) & 1u);   // RNE
  return (unsigned short)(r >> 16);
}

__device__ __forceinline__ float fast_gelu(float a){
  // exact-erf GELU via A&S 7.1.26 (|err| < 1.5e-7)
  float y = a * 0.70710678118654752f;
  float z = fabsf(y);
  float t = __frcp_rn(fmaf(0.3275911f, z, 1.f));
  float poly = t * fmaf(t, fmaf(t, fmaf(t, fmaf(t, 1.061405429f, -1.453152027f),
                                        1.421413741f), -0.284496736f), 0.254829592f);
  float e = __expf(-y * y);
  float erfz = 1.f - poly * e;
  float erfy = (y < 0.f) ? -erfz : erfz;
  return 0.5f * a * (1.f + erfy);
}

template<int C>
__device__ __forceinline__ void stage_w(const float* __restrict__ g,
                                        unsigned short* s, int R, int tid){
  for (int i = tid; i < R*C; i += 256){
    int row = i / C;                       // C is 64 or 128 -> shifts
    s[SWZ((unsigned)i * 2u, row) >> 1] = f2bf(g[i]);
  }
}

__global__ __launch_bounds__(256)
__attribute__((amdgpu_waves_per_eu(2)))
void mt_kernel(const float* __restrict__ z_m, const float* __restrict__ z_c,
               const float* __restrict__ z_t, const float* __restrict__ z_cls,
               const float* __restrict__ ipw, const float* __restrict__ ipb,
               const float* __restrict__ out_w, const float* __restrict__ out_b,
               const float* __restrict__ ln1_g, const float* __restrict__ ln1_b,
               const float* __restrict__ ln2_g, const float* __restrict__ ln2_b,
               const float* __restrict__ w1, const float* __restrict__ b1,
               const float* __restrict__ w2, const float* __restrict__ b2,
               float* __restrict__ h_out, float* __restrict__ aw_out, int M)
{
  __shared__ unsigned short ipw_s[192*64];  // 24576 B
  __shared__ unsigned short ow_s [64*64];   //  8192 B
  __shared__ unsigned short w1_s [128*64];  // 16384 B
  __shared__ unsigned short w2_s [64*128];  // 16384 B
  __shared__ unsigned short xn_s [4*16*64]; //  8192 B (per-wave 16x64)
  __shared__ unsigned short ctx_s[16*64];   //  2048 B
  __shared__ unsigned short yn_s [16*64];   //  2048 B
  __shared__ unsigned short h1_s [16*128];  //  4096 B   => 80 KB total

  const int tid = threadIdx.x;
  const int w   = tid >> 6;     // wave 0..3
  const int l   = tid & 63;
  const int p   = l >> 4;       // lane quarter 0..3
  const int c16 = l & 15;

  stage_w<64 >(ipw,   ipw_s, 192, tid);
  stage_w<64 >(out_w, ow_s,   64, tid);
  stage_w<64 >(w1,    w1_s,  128, tid);
  stage_w<128>(w2,    w2_s,   64, tid);
  __syncthreads();

  // ---- hoisted per-lane constants ----
  const int d0A = (l & 3) * 16;            // phase-A dims base (lane quarter of row)
  float ln1g[16], ln1b[16];
  #pragma unroll
  for (int i = 0; i < 16; ++i){ ln1g[i] = ln1_g[d0A+i]; ln1b[i] = ln1_b[d0A+i]; }
  float ipb_r[12];
  #pragma unroll
  for (int n = 0; n < 12; ++n) ipb_r[n] = ipb[c16 + 16*n];
  float zcob[16], ln2g[16], ln2b[16];
  #pragma unroll
  for (int mt = 0; mt < 4; ++mt)
    #pragma unroll
    for (int r = 0; r < 4; ++r){
      int e = 16*mt + 4*p + r;
      zcob[mt*4+r] = z_cls[e] + out_b[e];
      ln2g[mt*4+r] = ln2_g[e];  ln2b[mt*4+r] = ln2_b[e];
    }
  float b1r[8];
  #pragma unroll
  for (int tt = 0; tt < 2; ++tt)
    #pragma unroll
    for (int r = 0; r < 4; ++r) b1r[tt*4+r] = b1[16*(2*w+tt) + 4*p + r];
  float b2r[4];
  #pragma unroll
  for (int r = 0; r < 4; ++r) b2r[r] = b2[16*w + 4*p + r];

  unsigned short* xw = xn_s + w*1024;      // my wave's 16x64 xn region

  const int nT = M >> 4;                   // tiles of 16 groups
  for (int T = blockIdx.x; T < nT; T += gridDim.x){

    // ================= Phase A: load + LN1 -> xn (bf16, swizzled) ==========
    {
      const int t  = l >> 2;               // token row 0..15 in wave tile
      const int sq_ = t & 3;               // 0=cls,1=m,2=c,3=t
      const int g  = t >> 2;
      const int m  = T*16 + 4*w + g;
      const float* srcp;
      if      (sq_ == 0) srcp = z_cls + d0A;
      else if (sq_ == 1) srcp = z_m + (size_t)m*64 + d0A;
      else if (sq_ == 2) srcp = z_c + (size_t)m*64 + d0A;
      else               srcp = z_t + (size_t)m*64 + d0A;
      float xv[16];
      #pragma unroll
      for (int i = 0; i < 4; ++i){
        float4 q4 = ((const float4*)srcp)[i];
        xv[4*i+0]=q4.x; xv[4*i+1]=q4.y; xv[4*i+2]=q4.z; xv[4*i+3]=q4.w;
      }
      float sm = 0.f;
      #pragma unroll
      for (int i = 0; i < 16; ++i) sm += xv[i];
      sm += __shfl_xor(sm, 1); sm += __shfl_xor(sm, 2);
      float mu = sm * (1.f/64.f);
      float sq = 0.f;
      #pragma unroll
      for (int i = 0; i < 16; ++i){ float d = xv[i]-mu; sq = fmaf(d,d,sq); }
      sq += __shfl_xor(sq, 1); sq += __shfl_xor(sq, 2);
      float rstd = 1.f / sqrtf(sq * (1.f/64.f) + 1e-5f);
      us8 v0, v1;
      #pragma unroll
      for (int i = 0; i < 8; ++i)
        v0[i] = f2bf(fmaf((xv[i]-mu)*rstd, ln1g[i], ln1b[i]));
      #pragma unroll
      for (int i = 0; i < 8; ++i)
        v1[i] = f2bf(fmaf((xv[8+i]-mu)*rstd, ln1g[8+i], ln1b[8+i]));
      unsigned b0 = (unsigned)(t*64 + d0A) * 2u;
      *(us8*)&xw[SWZ(b0,      t) >> 1] = v0;
      *(us8*)&xw[SWZ(b0 + 16, t) >> 1] = v1;
    }
    __syncthreads();                       // B1

    // ================= qkv MFMA (my wave's 16 tokens) ======================
    f32x4 acc[12];
    #pragma unroll
    for (int n = 0; n < 12; ++n) acc[n] = (f32x4){0.f,0.f,0.f,0.f};
    {
      short8 a0 = *(const short8*)&xw[SWZ((c16*64 +      8*p)*2, c16) >> 1];
      short8 a1 = *(const short8*)&xw[SWZ((c16*64 + 32 + 8*p)*2, c16) >> 1];
      #pragma unroll
      for (int n = 0; n < 12; ++n){
        int e = c16 + 16*n;
        short8 b0 = *(const short8*)&ipw_s[SWZ((e*64 +      8*p)*2, e) >> 1];
        short8 b1v= *(const short8*)&ipw_s[SWZ((e*64 + 32 + 8*p)*2, e) >> 1];
        acc[n] = MFMA16(a0, b0, acc[n]);
        acc[n] = MFMA16(a1, b1v, acc[n]);
      }
      #pragma unroll
      for (int n = 0; n < 12; ++n){
        float bi = ipb_r[n];
        #pragma unroll
        for (int r = 0; r < 4; ++r) acc[n][r] += bi;
      }
    }
    // acc[n] C-layout: col=c16 (channel e=c16+16n), row=4p+r -> token of
    // group p (section), s=r. n=0..3: q heads, 4..7: k heads, 8..11: v heads.

    // ================= attention (per section = group) =====================
    float awm[16];
    #pragma unroll
    for (int i = 0; i < 16; ++i) awm[i] = 0.f;
    float ctx4[4];
    #pragma unroll
    for (int h = 0; h < 4; ++h){
      float sc[16];
      #pragma unroll
      for (int q = 0; q < 4; ++q)
        #pragma unroll
        for (int u = 0; u < 4; ++u) sc[q*4+u] = acc[h][q] * acc[4+h][u];
      #pragma unroll
      for (int st = 0; st < 4; ++st){      // sum over the 16 channel-lanes
        const int mask = 1 << st;
        #pragma unroll
        for (int i = 0; i < 16; ++i) sc[i] += __shfl_xor(sc[i], mask);
      }
      #pragma unroll
      for (int q = 0; q < 4; ++q){
        float s0 = sc[4*q+0]*0.25f, s1 = sc[4*q+1]*0.25f,
              s2 = sc[4*q+2]*0.25f, s3 = sc[4*q+3]*0.25f;
        float mx = fmaxf(fmaxf(s0,s1), fmaxf(s2,s3));
        s0 = __expf(s0-mx); s1 = __expf(s1-mx); s2 = __expf(s2-mx); s3 = __expf(s3-mx);
        float inv = 1.f/(s0+s1+s2+s3);
        s0*=inv; s1*=inv; s2*=inv; s3*=inv;
        sc[4*q+0]=s0; sc[4*q+1]=s1; sc[4*q+2]=s2; sc[4*q+3]=s3;
        awm[4*q+0]+=s0; awm[4*q+1]+=s1; awm[4*q+2]+=s2; awm[4*q+3]+=s3;
      }
      // row-0 ctx for head h: my channel c16+16h
      ctx4[h] = sc[0]*acc[8+h][0] + sc[1]*acc[8+h][1]
              + sc[2]*acc[8+h][2] + sc[3]*acc[8+h][3];
    }
    {
      const int m0 = T*16 + 4*w + p;
      if (c16 == 0){
        float4* ap = (float4*)(aw_out + (size_t)m0*16);
        ap[0] = make_float4(awm[0]*0.25f, awm[1]*0.25f, awm[2]*0.25f, awm[3]*0.25f);
        ap[1] = make_float4(awm[4]*0.25f, awm[5]*0.25f, awm[6]*0.25f, awm[7]*0.25f);
        ap[2] = make_float4(awm[8]*0.25f, awm[9]*0.25f, awm[10]*0.25f, awm[11]*0.25f);
        ap[3] = make_float4(awm[12]*0.25f, awm[13]*0.25f, awm[14]*0.25f, awm[15]*0.25f);
      }
      const int grow = 4*w + p;            // block-wide group row 0..15
      #pragma unroll
      for (int h = 0; h < 4; ++h)
        ctx_s[SWZ((grow*64 + c16 + 16*h)*2, grow) >> 1] = f2bf(ctx4[h]);
    }
    __syncthreads();                       // B2

    // ================= out-proj (weights-as-A, all waves) + LN2 ============
    f32x4 op[4];
    #pragma unroll
    for (int mt = 0; mt < 4; ++mt) op[mt] = (f32x4){0.f,0.f,0.f,0.f};
    {
      short8 cb0 = *(const short8*)&ctx_s[SWZ((c16*64 +      8*p)*2, c16) >> 1];
      short8 cb1 = *(const short8*)&ctx_s[SWZ((c16*64 + 32 + 8*p)*2, c16) >> 1];
      #pragma unroll
      for (int mt = 0; mt < 4; ++mt){
        int er = 16*mt + c16;
        short8 a0 = *(const short8*)&ow_s[SWZ((er*64 +      8*p)*2, er) >> 1];
        short8 a1 = *(const short8*)&ow_s[SWZ((er*64 + 32 + 8*p)*2, er) >> 1];
        op[mt] = MFMA16(a0, cb0, op[mt]);
        op[mt] = MFMA16(a1, cb1, op[mt]);
      }
    }
    // D[e][grow]: col=c16=group-row, e = 16*mt + 4*p + r
    float x0[16], x0w[4];
    #pragma unroll
    for (int mt = 0; mt < 4; ++mt)
      #pragma unroll
      for (int r = 0; r < 4; ++r) x0[mt*4+r] = op[mt][r] + zcob[mt*4+r];
    #pragma unroll
    for (int mt = 0; mt < 4; ++mt)
      if (mt == w){
        #pragma unroll
        for (int r = 0; r < 4; ++r) x0w[r] = x0[mt*4+r];
      }
    float sm2 = 0.f;
    #pragma unroll
    for (int i = 0; i < 16; ++i) sm2 += x0[i];
    sm2 += __shfl_xor(sm2, 16); sm2 += __shfl_xor(sm2, 32);
    float mu2 = sm2 * (1.f/64.f);
    float sq2 = 0.f;
    #pragma unroll
    for (int i = 0; i < 16; ++i){ float d = x0[i]-mu2; sq2 = fmaf(d,d,sq2); }
    sq2 += __shfl_xor(sq2, 16); sq2 += __shfl_xor(sq2, 32);
    float rstd2 = 1.f / sqrtf(sq2 * (1.f/64.f) + 1e-5f);
    if (w == 0){
      #pragma unroll
      for (int mt = 0; mt < 4; ++mt){
        us4 v;
        #pragma unroll
        for (int r = 0; r < 4; ++r)
          v[r] = f2bf(fmaf((x0[mt*4+r]-mu2)*rstd2, ln2g[mt*4+r], ln2b[mt*4+r]));
        *(us4*)&yn_s[SWZ((c16*64 + 16*mt + 4*p)*2, c16) >> 1] = v;
      }
    }
    __syncthreads();                       // B3

    // ================= FFN1 (wave w: e1 in [32w, 32w+32)) ==================
    f32x4 f1[2];
    #pragma unroll
    for (int tt = 0; tt < 2; ++tt) f1[tt] = (f32x4){0.f,0.f,0.f,0.f};
    {
      short8 yb0 = *(const short8*)&yn_s[SWZ((c16*64 +      8*p)*2, c16) >> 1];
      short8 yb1 = *(const short8*)&yn_s[SWZ((c16*64 + 32 + 8*p)*2, c16) >> 1];
      #pragma unroll
      for (int tt = 0; tt < 2; ++tt){
        int er = 16*(2*w+tt) + c16;
        short8 a0 = *(const short8*)&w1_s[SWZ((er*64 +      8*p)*2, er) >> 1];
        short8 a1 = *(const short8*)&w1_s[SWZ((er*64 + 32 + 8*p)*2, er) >> 1];
        f1[tt] = MFMA16(a0, yb0, f1[tt]);
        f1[tt] = MFMA16(a1, yb1, f1[tt]);
      }
    }
    #pragma unroll
    for (int tt = 0; tt < 2; ++tt){
      us4 v;
      #pragma unroll
      for (int r = 0; r < 4; ++r)
        v[r] = f2bf(fast_gelu(f1[tt][r] + b1r[tt*4+r]));
      *(us4*)&h1_s[SWZ((c16*128 + 16*(2*w+tt) + 4*p)*2, c16) >> 1] = v;
    }
    __syncthreads();                       // B4

    // ================= FFN2 (wave w: d in [16w,16w+16)) + store ============
    f32x4 f2 = (f32x4){0.f,0.f,0.f,0.f};
    {
      int ar = 16*w + c16;
      #pragma unroll
      for (int ks = 0; ks < 4; ++ks){
        short8 a = *(const short8*)&w2_s[SWZ((ar*128 + 32*ks + 8*p)*2, ar) >> 1];
        short8 b = *(const short8*)&h1_s[SWZ((c16*128 + 32*ks + 8*p)*2, c16) >> 1];
        f2 = MFMA16(a, b, f2);
      }
    }
    float4 ov;
    ov.x = x0w[0] + b2r[0] + f2[0];
    ov.y = x0w[1] + b2r[1] + f2[1];
    ov.z = x0w[2] + b2r[2] + f2[2];
    ov.w = x0w[3] + b2r[3] + f2[3];
    *(float4*)(h_out + (size_t)(T*16 + c16)*64 + 16*w + 4*p) = ov;
  }
}

extern "C" void kernel_launch(void* const* d_in, const int* in_sizes, int n_in,
                              void* d_out, int out_size, void* d_ws, size_t ws_size,
                              hipStream_t stream) {
  const float* z_m   = (const float*)d_in[0];
  const float* z_c   = (const float*)d_in[1];
  const float* z_t   = (const float*)d_in[2];
  const float* z_cls = (const float*)d_in[3];
  const float* ipw   = (const float*)d_in[4];
  const float* ipb   = (const float*)d_in[5];
  const float* out_w = (const float*)d_in[6];
  const float* out_b = (const float*)d_in[7];
  const float* ln1_g = (const float*)d_in[8];
  const float* ln1_b = (const float*)d_in[9];
  const float* ln2_g = (const float*)d_in[10];
  const float* ln2_b = (const float*)d_in[11];
  const float* w1    = (const float*)d_in[12];
  const float* b1    = (const float*)d_in[13];
  const float* w2    = (const float*)d_in[14];
  const float* b2    = (const float*)d_in[15];

  const int M = in_sizes[0] / 64;          // B*N groups (160000; divisible by 16)
  float* h_out  = (float*)d_out;           // (M,64)
  float* aw_out = h_out + (size_t)M * 64;  // (M,4,4)

  const int nT = M >> 4;
  int grid = nT < 512 ? nT : 512;          // 2 blocks/CU (80KB LDS), grid-stride

  hipLaunchKernelGGL(mt_kernel, dim3(grid), dim3(256), 0, stream,
                     z_m, z_c, z_t, z_cls, ipw, ipb, out_w, out_b,
                     ln1_g, ln1_b, ln2_g, ln2_b, w1, b1, w2, b2,
                     h_out, aw_out, M);
}